// Round 7
// baseline (3251.340 us; speedup 1.0000x reference)
//
#include <hip/hip_runtime.h>

typedef unsigned int u32;
typedef unsigned short u16;
typedef unsigned long long u64;
typedef __attribute__((ext_vector_type(8))) short short8;
typedef __attribute__((ext_vector_type(4))) float f32x4;
typedef __attribute__((ext_vector_type(4))) u32 u32x4;

#define SEQ 512
#define BATCH 32
#define DIM 1024
#define NB 128   // persistent blocks in recurrent kernel

// workspace layout (bytes)
#define OFF_XT    0ull                  // bf16 [16384][1024] Xt (dead after k_gemm)
                                        // -> REUSED: h slots s=0..511, 64KB each (32MB)
#define OFF_UBT   33554432ull           // bf16 [4096][1024] U^T (dead after k_gemm)
                                        // -> REUSED: h slot "-1" = zeros (64KB)
#define OFF_WG2   41943040ull           // bf16 [128 blk][64 grp][64 lane][8] frag-order W
#define OFF_XPROJ 50331648ull           // bf16 xp2 [512 s][128 blk][64 lane][16 slot]
#define OFF_BIAS  184680448ull          // f32  [4096]
#define OFF_SYNC  184696832ull          // u32 flags[128 blk][32] (128B-padded)

__device__ __forceinline__ float bf2f(u16 u) {
  union { u32 u; float f; } v; v.u = ((u32)u) << 16; return v.f;
}
__device__ __forceinline__ u16 f2bf(float f) {
  union { float f; u32 u; } v; v.f = f;
  u32 r = v.u + 0x7FFFu + ((v.u >> 16) & 1u);
  return (u16)(r >> 16);
}
// tanh(x) = 1 - 2/(1+e^{2x}) : exact identity, __expf-based
__device__ __forceinline__ float tanh_fast(float x) {
  return 1.f - 2.f / (1.f + __expf(2.f * x));
}
__device__ __forceinline__ void gload_lds16(const u16* g, u16* l) {
  __builtin_amdgcn_global_load_lds(
      (const __attribute__((address_space(1))) u32*)g,
      (__attribute__((address_space(3))) u32*)l, 16, 0, 0);
}
// LLC-coherent LDS-DMA: aux=17 = SC0|SC1 -> bypass L1+L2, read at LLC
__device__ __forceinline__ void gload_lds16_coh(const u16* g, u16* l) {
  __builtin_amdgcn_global_load_lds(
      (const __attribute__((address_space(1))) u32*)g,
      (__attribute__((address_space(3))) u32*)l, 16, 0, 17);
}

// ---------------- init: concat bias + zero flags --------------------------
__global__ void k_init(float* biasc, u32* sync, const float* bi,
                       const float* bfv, const float* bo, const float* bg) {
  int i = blockIdx.x * 256 + threadIdx.x;
  if (i < 4096) {
    int g = i >> 10, c = i & 1023;
    const float* p = (g == 0) ? bi : (g == 1) ? bfv : (g == 2) ? bo : bg;
    biasc[i] = p[c];
  } else if (i < 8192) {
    sync[i - 4096] = 0u;
  }
}

// ---------------- zero h slot -1 (UBT region; runs AFTER k_gemm) ----------
// zeros (any layout) == the step-0 initial h state. 16 blocks x 256 x 16B.
__global__ void k_zero(u32x4* p) {
  p[blockIdx.x * 256 + threadIdx.x] = (u32x4){0u, 0u, 0u, 0u};
}

// ---------------- transpose-cast the 8 weight matrices --------------------
// U matrices -> Ubt[e][k] row-major (k_gemm B operand)
// W matrices -> Wg2 MFMA-A-frag order per block, gate-dims reordered m=d'*4+g:
//   idx = blk*32768 + ((kt*2+rt)*64 + lane)*8 + j
//   kt=k>>5, rt=(c&7)>>2, lane=((k&31)>>3)*16 + (c&3)*4 + g, j=k&7
__global__ void k_prep_w(const float* Ui, const float* Wi, const float* Uf,
                         const float* Wf, const float* Uo, const float* Wo,
                         const float* Ug, const float* Wg, u16* Ubt, u16* Wg2) {
  __shared__ float tile[64][65];
  int bx = blockIdx.x;
  int mi = bx >> 8;               // matrix 0..7 (Ui,Wi,Uf,Wf,Uo,Wo,Ug,Wg)
  int tt = bx & 255;
  int tr = tt >> 4, tc = tt & 15; // 16x16 grid of 64x64 tiles
  const float* src;
  switch (mi) {
    case 0: src = Ui; break; case 1: src = Wi; break;
    case 2: src = Uf; break; case 3: src = Wf; break;
    case 4: src = Uo; break; case 5: src = Wo; break;
    case 6: src = Ug; break; default: src = Wg; break;
  }
  int g = mi >> 1;
  int d0 = tr * 64, c0 = tc * 64;
  int ty = threadIdx.x >> 6, tx = threadIdx.x & 63;
#pragma unroll
  for (int i = 0; i < 16; ++i) {
    int r = i * 4 + ty;
    tile[r][tx] = src[(size_t)(d0 + r) * 1024 + c0 + tx];
  }
  __syncthreads();
  if (mi & 1) {
#pragma unroll
    for (int i = 0; i < 16; ++i) {
      int cc = i * 4 + ty;
      int c_full = c0 + cc;           // W column (gate-dim) 0..1023
      int k = d0 + tx;                // W row (input dim) 0..1023
      int blk = c_full >> 3;
      int lane = (((k & 31) >> 3) << 4) + ((c_full & 3) << 2) + g;
      size_t idx = (size_t)blk * 32768 +
                   (size_t)(((k >> 5) * 2 + ((c_full & 7) >> 2)) * 64 + lane) * 8 +
                   (k & 7);
      Wg2[idx] = f2bf(tile[tx][cc]);
    }
  } else {
#pragma unroll
    for (int i = 0; i < 16; ++i) {
      int cc = i * 4 + ty;
      Ubt[(size_t)((g << 10) + c0 + cc) * 1024 + d0 + tx] = f2bf(tile[tx][cc]);
    }
  }
}

// ---------------- transpose-cast X: Xt[s*32+b][d] = X[b][s][d] ------------
__global__ void k_prep_x(const float* __restrict__ X, u16* __restrict__ Xt) {
  int idx = blockIdx.x * 256 + threadIdx.x;
  int m = idx >> 8, d4 = (idx & 255) << 2;
  int s = m >> 5, b = m & 31;
  const float4* p = (const float4*)(X + (size_t)(b * SEQ + s) * DIM + d4);
  float4 v = *p;
  u16 o[4] = { f2bf(v.x), f2bf(v.y), f2bf(v.z), f2bf(v.w) };
  *(ushort4*)(Xt + (size_t)m * DIM + d4) = *(ushort4*)o;
}

// ---------------- phase 1 GEMM: xp2 = per-lane-slot layout of Xt@U+b ------
// xp2 element for (s, b, col=g*1024+d):
//   addr = (s*128 + d>>3)*1024 + ((d&3)*16 + (b&15))*16 + (b>>4)*8 + ((d&7)>>2)*4 + g
__global__ __launch_bounds__(256) void k_gemm(const u16* __restrict__ Xt,
                                              const u16* __restrict__ Ubt,
                                              const float* __restrict__ biasc,
                                              u16* __restrict__ xp2) {
  __shared__ u16 As[128 * 32];
  __shared__ u16 Bs[128 * 32];
  int tid = threadIdx.x;
  int w = tid >> 6, l = tid & 63;
  int n0 = blockIdx.x * 128, m0 = blockIdx.y * 128;
  int wm = w >> 1, wn = w & 1;
  int lrow = l & 15, lq = l >> 4;
  f32x4 acc[4][4] = {};
  for (int kt = 0; kt < 32; ++kt) {
    int k0 = kt * 32;
    __syncthreads();
#pragma unroll
    for (int is = 0; is < 2; ++is) {
      int c = is * 256 + w * 64 + l;
      int row = c >> 2, kg = c & 3;
      gload_lds16(Xt + (size_t)(m0 + row) * 1024 + k0 + kg * 8, As + c * 8);
      gload_lds16(Ubt + (size_t)(n0 + row) * 1024 + k0 + kg * 8, Bs + c * 8);
    }
    __syncthreads();
    short8 af[4], bfr[4];
#pragma unroll
    for (int mt = 0; mt < 4; ++mt)
      af[mt] = *(const short8*)(As + (wm * 64 + mt * 16 + lrow) * 32 + lq * 8);
#pragma unroll
    for (int nt = 0; nt < 4; ++nt)
      bfr[nt] = *(const short8*)(Bs + (wn * 64 + nt * 16 + lrow) * 32 + lq * 8);
#pragma unroll
    for (int mt = 0; mt < 4; ++mt)
#pragma unroll
      for (int nt = 0; nt < 4; ++nt)
        acc[mt][nt] = __builtin_amdgcn_mfma_f32_16x16x32_bf16(
            af[mt], bfr[nt], acc[mt][nt], 0, 0, 0);
  }
#pragma unroll
  for (int nt = 0; nt < 4; ++nt) {
    int col = n0 + wn * 64 + nt * 16 + lrow;
    float bv = biasc[col];
    int g = col >> 10, d = col & 1023;
    int blkd = d >> 3;
    int slot = ((d & 7) >> 2) * 4 + g;    // rt*4 + g
    int lpart = (d & 3) * 16;             // q*16
#pragma unroll
    for (int mt = 0; mt < 4; ++mt) {
      int rbase = m0 + wm * 64 + mt * 16 + lq * 4;
#pragma unroll
      for (int r = 0; r < 4; ++r) {
        int row = rbase + r;
        int s = row >> 5, b = row & 31;
        xp2[(size_t)(s * 128 + blkd) * 1024 + (lpart + (b & 15)) * 16 +
            (b >> 4) * 8 + slot] = f2bf(acc[mt][nt][r] + bv);
      }
    }
  }
}

// ---------------- phase 2: persistent recurrent kernel (1 wave / block) ---
// R9 (resubmit; prior round was an infra failure, not a kernel result):
//   h staged via LDS-DMA (gload_lds16_coh, the R3/R4-proven path) into a
//   frag-linear Hs buffer instead of 256 VGPRs of inline-asm load results.
//   Single wave => vmcnt alone orders DMA -> ds_read; ZERO barriers.
//   Per-step: poll -> 64 DMA rounds -> 4-way vmcnt-split MFMA (128 mfma)
//   -> in-register gates -> 4 h-stores -> vmcnt(0) -> flag.
//   h slots are per-step (no double-buffer): no overwrite induction needed.
//   Hardening vs prior text: poll guard 20M -> 1M (fail-fast, ~40ms margin
//   is still 1000x any legitimate skew).
__global__ __launch_bounds__(64, 1) void k_rec(const u16* __restrict__ Wg2,
                                               const u16* __restrict__ xp2,
                                               u16* hX, const u16* __restrict__ h0,
                                               u32* sync) {
  __shared__ u16 Ws[32768];          // 64KB A-frag-order W slice (staged once)
  __shared__ u16 Hs[32768];          // 64KB B-frag-order h(s-1), re-staged
  int l = threadIdx.x;               // 0..63
  int blk = blockIdx.x;
  // stage W once (frag-linear: LDS dest = uniform base + lane*16B)
#pragma unroll
  for (int it = 0; it < 64; ++it)
    gload_lds16(Wg2 + (size_t)blk * 32768 + it * 512 + l * 8,
                Ws + it * 512 + l * 8);
  // xq for s=0 (only 8 asm-load VGPRs live across waits -- no spill window)
  u32x4 xqc0, xqc1, xqn0, xqn1;
  {
    const u16* xp = xp2 + (size_t)blk * 1024 + l * 16;
    asm volatile("global_load_dwordx4 %0, %1, off" : "=v"(xqc0) : "v"(xp));
    asm volatile("global_load_dwordx4 %0, %1, off" : "=v"(xqc1) : "v"(xp + 8));
  }
  asm volatile("s_waitcnt vmcnt(0)" ::: "memory");
  __builtin_amdgcn_sched_barrier(0);

  int q = l >> 4, b15 = l & 15;
  // producer h-store offsets (hfrag addr for (d=blk*8+rt*4+q, b=ct*16+b15)):
  //   ((blk>>2)*2 + ct)*512 + ((blk&3)*16 + b15)*8 + rt*4 + q
  int hoff0 = (((blk >> 2) * 2 + 0) * 64 + (blk & 3) * 16 + b15) * 8 + q; // ct0,rt0
  int hoff1 = (((blk >> 2) * 2 + 1) * 64 + (blk & 3) * 16 + b15) * 8 + q; // ct1,rt0
  float c00 = 0.f, c01 = 0.f, c10 = 0.f, c11 = 0.f;  // c_reg[rt][ct]

  for (int s = 0; s < SEQ; ++s) {
    // ---- poll all 128 flags >= s (lane covers flags l, l+64) -------------
    {
      u32 tgt = (u32)s;
      int guard = 0;
      for (;;) {
        u32 a = __hip_atomic_load(sync + l * 32, __ATOMIC_RELAXED,
                                  __HIP_MEMORY_SCOPE_AGENT);
        u32 b = __hip_atomic_load(sync + (64 + l) * 32, __ATOMIC_RELAXED,
                                  __HIP_MEMORY_SCOPE_AGENT);
        if (a >= tgt && b >= tgt) break;
        __builtin_amdgcn_s_sleep(1);
        if (++guard > 1000000) break;    // fail-fast anti-hang bailout
      }
    }
    asm volatile("" ::: "memory");
    __builtin_amdgcn_sched_barrier(0);

    const u16* hs = (s == 0) ? h0 : (hX + (size_t)(s - 1) * 32768);
    // ---- 64 coherent DMA rounds: hfrag tile g2 -> Hs (frag-linear) -------
#pragma unroll
    for (int g2 = 0; g2 < 64; ++g2)
      gload_lds16_coh(hs + g2 * 512 + l * 8, Hs + g2 * 512 + l * 8);
    // xq(s+1) prefetch (youngest 2 vmem entries; fly through MFMA phase)
    {
      int sp = (s + 1 < SEQ) ? s + 1 : s;
      const u16* xp = xp2 + ((size_t)sp * 128 + blk) * 1024 + l * 16;
      asm volatile("global_load_dwordx4 %0, %1, off" : "=v"(xqn0) : "v"(xp));
      asm volatile("global_load_dwordx4 %0, %1, off" : "=v"(xqn1) : "v"(xp + 8));
    }

    f32x4 a00 = {0.f,0.f,0.f,0.f}, a01 = {0.f,0.f,0.f,0.f};
    f32x4 a10 = {0.f,0.f,0.f,0.f}, a11 = {0.f,0.f,0.f,0.f};
    // 4-way vmcnt split: issue total = 64 DMA + 2 xq = 66.
    //   vmcnt(50): oldest 16 done (tiles 0..15)  -> kt 0..7
    //   vmcnt(34): tiles 0..31                   -> kt 8..15
    //   vmcnt(18): tiles 0..47                   -> kt 16..23
    //   vmcnt(2) : all 64 tiles (xq still flying)-> kt 24..31
#define MFMA_CHUNK(KT0, KT1)                                               \
    _Pragma("unroll")                                                      \
    for (int kt = (KT0); kt < (KT1); ++kt) {                               \
      short8 w0 = *(const short8*)(Ws + (kt * 2 + 0) * 512 + l * 8);       \
      short8 w1 = *(const short8*)(Ws + (kt * 2 + 1) * 512 + l * 8);       \
      short8 b0 = *(const short8*)(Hs + (kt * 2 + 0) * 512 + l * 8);       \
      short8 b1 = *(const short8*)(Hs + (kt * 2 + 1) * 512 + l * 8);       \
      a00 = __builtin_amdgcn_mfma_f32_16x16x32_bf16(w0, b0, a00, 0, 0, 0); \
      a01 = __builtin_amdgcn_mfma_f32_16x16x32_bf16(w0, b1, a01, 0, 0, 0); \
      a10 = __builtin_amdgcn_mfma_f32_16x16x32_bf16(w1, b0, a10, 0, 0, 0); \
      a11 = __builtin_amdgcn_mfma_f32_16x16x32_bf16(w1, b1, a11, 0, 0, 0); \
    }
    asm volatile("s_waitcnt vmcnt(50)" ::: "memory");
    __builtin_amdgcn_sched_barrier(0);
    MFMA_CHUNK(0, 8)
    asm volatile("s_waitcnt vmcnt(34)" ::: "memory");
    __builtin_amdgcn_sched_barrier(0);
    MFMA_CHUNK(8, 16)
    asm volatile("s_waitcnt vmcnt(18)" ::: "memory");
    __builtin_amdgcn_sched_barrier(0);
    MFMA_CHUNK(16, 24)
    asm volatile("s_waitcnt vmcnt(2)" ::: "memory");
    __builtin_amdgcn_sched_barrier(0);
    MFMA_CHUNK(24, 32)
#undef MFMA_CHUNK

    // ---- gates fully in registers: a{rt}{ct}[reg] = {zi,zf,zo,zg} --------
    union { u32x4 v[2]; u16 a[16]; } xq;
    xq.v[0] = xqc0; xq.v[1] = xqc1;    // slot e = ct*8 + rt*4 + gate
    float h00, h01, h10, h11;
#define CELL(AC, CR, HV, CT, RT)                                           \
    {                                                                      \
      float zi = AC[0] + bf2f(xq.a[(CT)*8 + (RT)*4 + 0]);                  \
      float zf = AC[1] + bf2f(xq.a[(CT)*8 + (RT)*4 + 1]);                  \
      float zo = AC[2] + bf2f(xq.a[(CT)*8 + (RT)*4 + 2]);                  \
      float zg = AC[3] + bf2f(xq.a[(CT)*8 + (RT)*4 + 3]);                  \
      float ig = 1.f / (1.f + __expf(-zi));                                \
      float fg = 1.f / (1.f + __expf(-zf));                                \
      float og = 1.f / (1.f + __expf(-zo));                                \
      float gg = tanh_fast(zg);                                            \
      CR = 1.f / (1.f + __expf(-(fg * CR + ig * gg)));                     \
      HV = tanh_fast(CR) * og;                                             \
    }
    CELL(a00, c00, h00, 0, 0)
    CELL(a01, c01, h01, 1, 0)
    CELL(a10, c10, h10, 0, 1)
    CELL(a11, c11, h11, 1, 1)
#undef CELL

    // ---- 4 fire-and-forget h-stores into slot s, one ack wait, flag ------
    u16* hn = hX + (size_t)s * 32768;
    __hip_atomic_store(hn + hoff0,     f2bf(h00), __ATOMIC_RELAXED,
                       __HIP_MEMORY_SCOPE_AGENT);
    __hip_atomic_store(hn + hoff1,     f2bf(h01), __ATOMIC_RELAXED,
                       __HIP_MEMORY_SCOPE_AGENT);
    __hip_atomic_store(hn + hoff0 + 4, f2bf(h10), __ATOMIC_RELAXED,
                       __HIP_MEMORY_SCOPE_AGENT);
    __hip_atomic_store(hn + hoff1 + 4, f2bf(h11), __ATOMIC_RELAXED,
                       __HIP_MEMORY_SCOPE_AGENT);
    asm volatile("s_waitcnt vmcnt(0)" ::: "memory");   // h acked (+xq drained)
    __builtin_amdgcn_sched_barrier(0);
    if (l == 0)
      __hip_atomic_store(sync + blk * 32, (u32)(s + 1), __ATOMIC_RELAXED,
                         __HIP_MEMORY_SCOPE_AGENT);
    xqc0 = xqn0; xqc1 = xqn1;
  }
}

// ---------------- phase 3: relayout h history -> out (f32) ----------------
__global__ void k_out(const u16* __restrict__ hx, float* __restrict__ out) {
  int t = blockIdx.x * 256 + threadIdx.x;    // 2,097,152 threads, 8 elems each
  int d0 = (t & 127) << 3;
  int rem = t >> 7;
  int s = rem & 511, b = rem >> 9;
  int kt = d0 >> 5, jg = (d0 & 31) >> 3, ct = b >> 4;
  const u16* src = hx + (size_t)s * 32768 +
                   (size_t)(((kt * 2 + ct) * 64 + jg * 16 + (b & 15)) * 8);
  ushort4 v0 = *(const ushort4*)src;
  ushort4 v1 = *(const ushort4*)(src + 4);
  float4 o0 = { bf2f(v0.x), bf2f(v0.y), bf2f(v0.z), bf2f(v0.w) };
  float4 o1 = { bf2f(v1.x), bf2f(v1.y), bf2f(v1.z), bf2f(v1.w) };
  float* dst = out + (size_t)(b * SEQ + s) * DIM + d0;
  *(float4*)dst = o0;
  *(float4*)(dst + 4) = o1;
}

// ---------------------------------------------------------------------------
extern "C" void kernel_launch(void* const* d_in, const int* in_sizes, int n_in,
                              void* d_out, int out_size, void* d_ws,
                              size_t ws_size, hipStream_t stream) {
  const float* X   = (const float*)d_in[0];
  const float* Ui  = (const float*)d_in[1];
  const float* Wi  = (const float*)d_in[2];
  const float* Uf  = (const float*)d_in[3];
  const float* Wf  = (const float*)d_in[4];
  const float* Uo  = (const float*)d_in[5];
  const float* Wo  = (const float*)d_in[6];
  const float* Ug  = (const float*)d_in[7];
  const float* Wg  = (const float*)d_in[8];
  const float* bi  = (const float*)d_in[9];
  const float* bfv = (const float*)d_in[10];
  const float* bo  = (const float*)d_in[11];
  const float* bg  = (const float*)d_in[12];
  char* ws = (char*)d_ws;
  u16* Xt      = (u16*)(ws + OFF_XT);      // Xt for gemm; then h slots 0..511
  u16* Ubt     = (u16*)(ws + OFF_UBT);     // U^T for gemm; then h slot -1 (zeros)
  u16* Wg2     = (u16*)(ws + OFF_WG2);
  u16* xp2     = (u16*)(ws + OFF_XPROJ);
  float* biasc = (float*)(ws + OFF_BIAS);
  u32* sync    = (u32*)(ws + OFF_SYNC);
  float* out   = (float*)d_out;

  k_init<<<32, 256, 0, stream>>>(biasc, sync, bi, bfv, bo, bg);
  k_prep_w<<<2048, 256, 0, stream>>>(Ui, Wi, Uf, Wf, Uo, Wo, Ug, Wg, Ubt, Wg2);
  k_prep_x<<<16384, 256, 0, stream>>>(X, Xt);
  k_gemm<<<dim3(32, 128), 256, 0, stream>>>(Xt, Ubt, biasc, xp2);
  k_zero<<<16, 256, 0, stream>>>((u32x4*)Ubt);   // after gemm: Ubt dead -> zeros
  k_rec<<<NB, 64, 0, stream>>>(Wg2, xp2, Xt, Ubt, sync);
  k_out<<<8192, 256, 0, stream>>>(Xt, out);
}

// Round 8
// 2107.322 us; speedup vs baseline: 1.5429x; 1.5429x over previous
//
#include <hip/hip_runtime.h>

typedef unsigned int u32;
typedef unsigned short u16;
typedef unsigned long long u64;
typedef __attribute__((ext_vector_type(8))) short short8;
typedef __attribute__((ext_vector_type(4))) float f32x4;
typedef __attribute__((ext_vector_type(4))) u32 u32x4;
typedef __attribute__((ext_vector_type(2))) u32 u32x2;

#define SEQ 512
#define BATCH 32
#define DIM 1024
#define NB 128   // persistent blocks in recurrent kernel

// workspace layout (bytes)
#define OFF_XT    0ull                  // bf16 [16384][1024] Xt (dead after k_gemm)
                                        // -> REUSED: h slots s=0..511, 64KB each (32MB)
#define OFF_UBT   33554432ull           // bf16 [4096][1024] U^T (dead after k_gemm)
                                        // -> REUSED: h slot "-1" = zeros (64KB)
#define OFF_WG2   41943040ull           // bf16 [128 blk][64 grp][64 lane][8] frag-order W
#define OFF_XPROJ 50331648ull           // bf16 xp2 [512 s][128 blk][64 lane][16 slot]
#define OFF_BIAS  184680448ull          // f32  [4096]
#define OFF_SYNC  184696832ull          // u32 flags[128 blk][32] (128B-padded)

__device__ __forceinline__ float bf2f(u16 u) {
  union { u32 u; float f; } v; v.u = ((u32)u) << 16; return v.f;
}
__device__ __forceinline__ u16 f2bf(float f) {
  union { float f; u32 u; } v; v.f = f;
  u32 r = v.u + 0x7FFFu + ((v.u >> 16) & 1u);
  return (u16)(r >> 16);
}
// tanh(x) = 1 - 2/(1+e^{2x}) : exact identity, __expf-based
__device__ __forceinline__ float tanh_fast(float x) {
  return 1.f - 2.f / (1.f + __expf(2.f * x));
}
__device__ __forceinline__ void gload_lds16(const u16* g, u16* l) {
  __builtin_amdgcn_global_load_lds(
      (const __attribute__((address_space(1))) u32*)g,
      (__attribute__((address_space(3))) u32*)l, 16, 0, 0);
}
// LLC-coherent LDS-DMA: aux=17 = SC0|SC1 -> bypass L1+L2, read at LLC
__device__ __forceinline__ void gload_lds16_coh(const u16* g, u16* l) {
  __builtin_amdgcn_global_load_lds(
      (const __attribute__((address_space(1))) u32*)g,
      (__attribute__((address_space(3))) u32*)l, 16, 0, 17);
}

// ---------------- init: concat bias + zero flags --------------------------
__global__ void k_init(float* biasc, u32* sync, const float* bi,
                       const float* bfv, const float* bo, const float* bg) {
  int i = blockIdx.x * 256 + threadIdx.x;
  if (i < 4096) {
    int g = i >> 10, c = i & 1023;
    const float* p = (g == 0) ? bi : (g == 1) ? bfv : (g == 2) ? bo : bg;
    biasc[i] = p[c];
  } else if (i < 8192) {
    sync[i - 4096] = 0u;
  }
}

// ---------------- zero h slot -1 (UBT region; runs AFTER k_gemm) ----------
__global__ void k_zero(u32x4* p) {
  p[blockIdx.x * 256 + threadIdx.x] = (u32x4){0u, 0u, 0u, 0u};
}

// ---------------- transpose-cast the 8 weight matrices --------------------
// U matrices -> Ubt[e][k] row-major (k_gemm B operand)
// W matrices -> Wg2 MFMA-A-frag order per block, gate-dims reordered m=d'*4+g:
//   idx = blk*32768 + ((kt*2+rt)*64 + lane)*8 + j
//   kt=k>>5, rt=(c&7)>>2, lane=((k&31)>>3)*16 + (c&3)*4 + g, j=k&7
__global__ void k_prep_w(const float* Ui, const float* Wi, const float* Uf,
                         const float* Wf, const float* Uo, const float* Wo,
                         const float* Ug, const float* Wg, u16* Ubt, u16* Wg2) {
  __shared__ float tile[64][65];
  int bx = blockIdx.x;
  int mi = bx >> 8;               // matrix 0..7 (Ui,Wi,Uf,Wf,Uo,Wo,Ug,Wg)
  int tt = bx & 255;
  int tr = tt >> 4, tc = tt & 15; // 16x16 grid of 64x64 tiles
  const float* src;
  switch (mi) {
    case 0: src = Ui; break; case 1: src = Wi; break;
    case 2: src = Uf; break; case 3: src = Wf; break;
    case 4: src = Uo; break; case 5: src = Wo; break;
    case 6: src = Ug; break; default: src = Wg; break;
  }
  int g = mi >> 1;
  int d0 = tr * 64, c0 = tc * 64;
  int ty = threadIdx.x >> 6, tx = threadIdx.x & 63;
#pragma unroll
  for (int i = 0; i < 16; ++i) {
    int r = i * 4 + ty;
    tile[r][tx] = src[(size_t)(d0 + r) * 1024 + c0 + tx];
  }
  __syncthreads();
  if (mi & 1) {
#pragma unroll
    for (int i = 0; i < 16; ++i) {
      int cc = i * 4 + ty;
      int c_full = c0 + cc;           // W column (gate-dim) 0..1023
      int k = d0 + tx;                // W row (input dim) 0..1023
      int blk = c_full >> 3;
      int lane = (((k & 31) >> 3) << 4) + ((c_full & 3) << 2) + g;
      size_t idx = (size_t)blk * 32768 +
                   (size_t)(((k >> 5) * 2 + ((c_full & 7) >> 2)) * 64 + lane) * 8 +
                   (k & 7);
      Wg2[idx] = f2bf(tile[tx][cc]);
    }
  } else {
#pragma unroll
    for (int i = 0; i < 16; ++i) {
      int cc = i * 4 + ty;
      Ubt[(size_t)((g << 10) + c0 + cc) * 1024 + d0 + tx] = f2bf(tile[tx][cc]);
    }
  }
}

// ---------------- transpose-cast X: Xt[s*32+b][d] = X[b][s][d] ------------
__global__ void k_prep_x(const float* __restrict__ X, u16* __restrict__ Xt) {
  int idx = blockIdx.x * 256 + threadIdx.x;
  int m = idx >> 8, d4 = (idx & 255) << 2;
  int s = m >> 5, b = m & 31;
  const float4* p = (const float4*)(X + (size_t)(b * SEQ + s) * DIM + d4);
  float4 v = *p;
  u16 o[4] = { f2bf(v.x), f2bf(v.y), f2bf(v.z), f2bf(v.w) };
  *(ushort4*)(Xt + (size_t)m * DIM + d4) = *(ushort4*)o;
}

// ---------------- phase 1 GEMM: xp2 = per-lane-slot layout of Xt@U+b ------
// xp2 element for (s, b, col=g*1024+d):
//   addr = (s*128 + d>>3)*1024 + ((d&3)*16 + (b&15))*16 + (b>>4)*8 + ((d&7)>>2)*4 + g
__global__ __launch_bounds__(256) void k_gemm(const u16* __restrict__ Xt,
                                              const u16* __restrict__ Ubt,
                                              const float* __restrict__ biasc,
                                              u16* __restrict__ xp2) {
  __shared__ u16 As[128 * 32];
  __shared__ u16 Bs[128 * 32];
  int tid = threadIdx.x;
  int w = tid >> 6, l = tid & 63;
  int n0 = blockIdx.x * 128, m0 = blockIdx.y * 128;
  int wm = w >> 1, wn = w & 1;
  int lrow = l & 15, lq = l >> 4;
  f32x4 acc[4][4] = {};
  for (int kt = 0; kt < 32; ++kt) {
    int k0 = kt * 32;
    __syncthreads();
#pragma unroll
    for (int is = 0; is < 2; ++is) {
      int c = is * 256 + w * 64 + l;
      int row = c >> 2, kg = c & 3;
      gload_lds16(Xt + (size_t)(m0 + row) * 1024 + k0 + kg * 8, As + c * 8);
      gload_lds16(Ubt + (size_t)(n0 + row) * 1024 + k0 + kg * 8, Bs + c * 8);
    }
    __syncthreads();
    short8 af[4], bfr[4];
#pragma unroll
    for (int mt = 0; mt < 4; ++mt)
      af[mt] = *(const short8*)(As + (wm * 64 + mt * 16 + lrow) * 32 + lq * 8);
#pragma unroll
    for (int nt = 0; nt < 4; ++nt)
      bfr[nt] = *(const short8*)(Bs + (wn * 64 + nt * 16 + lrow) * 32 + lq * 8);
#pragma unroll
    for (int mt = 0; mt < 4; ++mt)
#pragma unroll
      for (int nt = 0; nt < 4; ++nt)
        acc[mt][nt] = __builtin_amdgcn_mfma_f32_16x16x32_bf16(
            af[mt], bfr[nt], acc[mt][nt], 0, 0, 0);
  }
#pragma unroll
  for (int nt = 0; nt < 4; ++nt) {
    int col = n0 + wn * 64 + nt * 16 + lrow;
    float bv = biasc[col];
    int g = col >> 10, d = col & 1023;
    int blkd = d >> 3;
    int slot = ((d & 7) >> 2) * 4 + g;    // rt*4 + g
    int lpart = (d & 3) * 16;             // q*16
#pragma unroll
    for (int mt = 0; mt < 4; ++mt) {
      int rbase = m0 + wm * 64 + mt * 16 + lq * 4;
#pragma unroll
      for (int r = 0; r < 4; ++r) {
        int row = rbase + r;
        int s = row >> 5, b = row & 31;
        xp2[(size_t)(s * 128 + blkd) * 1024 + (lpart + (b & 15)) * 16 +
            (b >> 4) * 8 + slot] = f2bf(acc[mt][nt][r] + bv);
      }
    }
  }
}

// ---------------- phase 2: persistent recurrent kernel (4 waves / block) --
// R10 hybrid: R4's proven 4-wave flag+DMA exchange protocol + R9's verified
// frag layouts.  Wave (mt,nt) computes the 16x16 (z-col, batch) quadrant:
//   - W held in VGPRs (32 short8/lane, A-frag order, staged once)
//   - h staged cooperatively 64KB/step into Hs (frag-linear coherent DMA);
//     round it, wave w stages tile it*4+w -> rounds 0-7 across waves = tiles
//     0-31, enabling the T3 split: vmcnt(9)+s_barrier -> MFMA kt0-15 ->
//     vmcnt(1)+s_barrier -> MFMA kt16-31
//   - each lane's f32x4 acc = 4 gates of ONE cell (batch nt*16+(l&15),
//     dim blk*8+mt*4+(l>>4)) -> gates fully in registers, no zbuf barrier
//   - 1 h-store per thread (frag addr, R9-verified formula), __syncthreads
//     drains it, tid0 sets flag.  Out-relayout offloaded to k_out.
__global__ __launch_bounds__(256, 1) void k_rec(const u16* __restrict__ Wg2,
                                                const u16* __restrict__ xp2,
                                                u16* hX, const u16* __restrict__ h0,
                                                u32* sync) {
  __shared__ u16 Hs[32768];          // 64KB B-frag-order h(s-1), re-staged
  int tid = threadIdx.x;
  int w = tid >> 6, l = tid & 63;
  int mt = w >> 1, nt = w & 1;
  int blk = blockIdx.x;
  int q = l >> 4, b15 = l & 15;

  // ---- stage W into registers (A-frag tiles kt*2+mt), static unroll ------
  short8 wf[32];
#pragma unroll
  for (int kt = 0; kt < 32; ++kt)
    wf[kt] = *(const short8*)(Wg2 + (size_t)blk * 32768 + (kt * 2 + mt) * 512 +
                              l * 8);
  // xq for s=0 (per-thread 8B: 4 gates of this thread's cell)
  u32x2 xqc, xqn;
  {
    const u16* xp = xp2 + (size_t)blk * 1024 + l * 16 + nt * 8 + mt * 4;
    asm volatile("global_load_dwordx2 %0, %1, off" : "=v"(xqc) : "v"(xp));
  }
  asm volatile("s_waitcnt vmcnt(0)" ::: "memory");
  __builtin_amdgcn_sched_barrier(0);

  // producer h-store offset for cell (d=blk*8+mt*4+q, b=nt*16+b15)
  // (R9-verified formula with rt->mt, ct->nt)
  int hoff = (((blk >> 2) * 2 + nt) * 64 + (blk & 3) * 16 + b15) * 8 + mt * 4 + q;
  float c_reg = 0.f;

  for (int s = 0; s < SEQ; ++s) {
    // ---- poll all 128 flags >= s (lane covers flags l, l+64) -------------
    {
      u32 tgt = (u32)s;
      int guard = 0;
      for (;;) {
        u32 a = __hip_atomic_load(sync + l * 32, __ATOMIC_RELAXED,
                                  __HIP_MEMORY_SCOPE_AGENT);
        u32 b = __hip_atomic_load(sync + (64 + l) * 32, __ATOMIC_RELAXED,
                                  __HIP_MEMORY_SCOPE_AGENT);
        if (a >= tgt && b >= tgt) break;
        __builtin_amdgcn_s_sleep(1);
        if (++guard > 1000000) break;    // fail-fast anti-hang bailout
      }
    }
    asm volatile("" ::: "memory");
    __builtin_amdgcn_sched_barrier(0);

    const u16* hs = (s == 0) ? h0 : (hX + (size_t)(s - 1) * 32768);
    // ---- 16 coherent DMA rounds (cooperative): round it = tiles it*4+w ---
#pragma unroll
    for (int it = 0; it < 16; ++it)
      gload_lds16_coh(hs + (it * 256 + tid) * 8, Hs + (it * 256 + tid) * 8);
    // xq(s+1) prefetch (youngest vmem entry; flies through MFMA phase)
    {
      int sp = (s + 1 < SEQ) ? s + 1 : s;
      const u16* xp = xp2 + ((size_t)sp * 128 + blk) * 1024 + l * 16 +
                      nt * 8 + mt * 4;
      asm volatile("global_load_dwordx2 %0, %1, off" : "=v"(xqn) : "v"(xp));
    }

    f32x4 a0 = {0.f, 0.f, 0.f, 0.f}, a1 = {0.f, 0.f, 0.f, 0.f};
    // rounds 0-7 done (9 younger outstanding: rounds 8-15 + xqn) -> tiles 0-31
    asm volatile("s_waitcnt vmcnt(9)" ::: "memory");
    __builtin_amdgcn_sched_barrier(0);
    __builtin_amdgcn_s_barrier();
    __builtin_amdgcn_sched_barrier(0);
#pragma unroll
    for (int kt = 0; kt < 16; kt += 2) {
      short8 b0 = *(const short8*)(Hs + (kt * 2 + nt) * 512 + l * 8);
      short8 b1 = *(const short8*)(Hs + ((kt + 1) * 2 + nt) * 512 + l * 8);
      a0 = __builtin_amdgcn_mfma_f32_16x16x32_bf16(wf[kt], b0, a0, 0, 0, 0);
      a1 = __builtin_amdgcn_mfma_f32_16x16x32_bf16(wf[kt + 1], b1, a1, 0, 0, 0);
    }
    // all DMA done (only xqn flying)
    asm volatile("s_waitcnt vmcnt(1)" ::: "memory");
    __builtin_amdgcn_sched_barrier(0);
    __builtin_amdgcn_s_barrier();
    __builtin_amdgcn_sched_barrier(0);
#pragma unroll
    for (int kt = 16; kt < 32; kt += 2) {
      short8 b0 = *(const short8*)(Hs + (kt * 2 + nt) * 512 + l * 8);
      short8 b1 = *(const short8*)(Hs + ((kt + 1) * 2 + nt) * 512 + l * 8);
      a0 = __builtin_amdgcn_mfma_f32_16x16x32_bf16(wf[kt], b0, a0, 0, 0, 0);
      a1 = __builtin_amdgcn_mfma_f32_16x16x32_bf16(wf[kt + 1], b1, a1, 0, 0, 0);
    }
    f32x4 z4 = a0 + a1;

    // ---- gates fully in registers: z4 = {zi,zf,zo,zg} of this cell -------
    union { u32x2 v; u16 a[4]; } xq;
    xq.v = xqc;
    float zi = z4[0] + bf2f(xq.a[0]);
    float zf = z4[1] + bf2f(xq.a[1]);
    float zo = z4[2] + bf2f(xq.a[2]);
    float zg = z4[3] + bf2f(xq.a[3]);
    float ig = 1.f / (1.f + __expf(-zi));
    float fg = 1.f / (1.f + __expf(-zf));
    float og = 1.f / (1.f + __expf(-zo));
    float gg = tanh_fast(zg);
    c_reg = 1.f / (1.f + __expf(-(fg * c_reg + ig * gg)));  // nonstandard cell
    float h = tanh_fast(c_reg) * og;

    // ---- 1 fire-and-forget h-store, drain via syncthreads, flag ----------
    __hip_atomic_store(hX + (size_t)s * 32768 + hoff, f2bf(h),
                       __ATOMIC_RELAXED, __HIP_MEMORY_SCOPE_AGENT);
    __syncthreads();                 // vmcnt(0)+lgkmcnt(0)+barrier: h acked
    if (tid == 0)
      __hip_atomic_store(sync + blk * 32, (u32)(s + 1), __ATOMIC_RELAXED,
                         __HIP_MEMORY_SCOPE_AGENT);
    xqc = xqn;
  }
}

// ---------------- phase 3: relayout h history -> out (f32) ----------------
__global__ void k_out(const u16* __restrict__ hx, float* __restrict__ out) {
  int t = blockIdx.x * 256 + threadIdx.x;    // 2,097,152 threads, 8 elems each
  int d0 = (t & 127) << 3;
  int rem = t >> 7;
  int s = rem & 511, b = rem >> 9;
  int kt = d0 >> 5, jg = (d0 & 31) >> 3, ct = b >> 4;
  const u16* src = hx + (size_t)s * 32768 +
                   (size_t)(((kt * 2 + ct) * 64 + jg * 16 + (b & 15)) * 8);
  ushort4 v0 = *(const ushort4*)src;
  ushort4 v1 = *(const ushort4*)(src + 4);
  float4 o0 = { bf2f(v0.x), bf2f(v0.y), bf2f(v0.z), bf2f(v0.w) };
  float4 o1 = { bf2f(v1.x), bf2f(v1.y), bf2f(v1.z), bf2f(v1.w) };
  float* dst = out + (size_t)(b * SEQ + s) * DIM + d0;
  *(float4*)dst = o0;
  *(float4*)(dst + 4) = o1;
}

// ---------------------------------------------------------------------------
extern "C" void kernel_launch(void* const* d_in, const int* in_sizes, int n_in,
                              void* d_out, int out_size, void* d_ws,
                              size_t ws_size, hipStream_t stream) {
  const float* X   = (const float*)d_in[0];
  const float* Ui  = (const float*)d_in[1];
  const float* Wi  = (const float*)d_in[2];
  const float* Uf  = (const float*)d_in[3];
  const float* Wf  = (const float*)d_in[4];
  const float* Uo  = (const float*)d_in[5];
  const float* Wo  = (const float*)d_in[6];
  const float* Ug  = (const float*)d_in[7];
  const float* Wg  = (const float*)d_in[8];
  const float* bi  = (const float*)d_in[9];
  const float* bfv = (const float*)d_in[10];
  const float* bo  = (const float*)d_in[11];
  const float* bg  = (const float*)d_in[12];
  char* ws = (char*)d_ws;
  u16* Xt      = (u16*)(ws + OFF_XT);      // Xt for gemm; then h slots 0..511
  u16* Ubt     = (u16*)(ws + OFF_UBT);     // U^T for gemm; then h slot -1 (zeros)
  u16* Wg2     = (u16*)(ws + OFF_WG2);
  u16* xp2     = (u16*)(ws + OFF_XPROJ);
  float* biasc = (float*)(ws + OFF_BIAS);
  u32* sync    = (u32*)(ws + OFF_SYNC);
  float* out   = (float*)d_out;

  k_init<<<32, 256, 0, stream>>>(biasc, sync, bi, bfv, bo, bg);
  k_prep_w<<<2048, 256, 0, stream>>>(Ui, Wi, Uf, Wf, Uo, Wo, Ug, Wg, Ubt, Wg2);
  k_prep_x<<<16384, 256, 0, stream>>>(X, Xt);
  k_gemm<<<dim3(32, 128), 256, 0, stream>>>(Xt, Ubt, biasc, xp2);
  k_zero<<<16, 256, 0, stream>>>((u32x4*)Ubt);   // after gemm: Ubt dead -> zeros
  k_rec<<<NB, 256, 0, stream>>>(Wg2, xp2, Xt, Ubt, sync);
  k_out<<<8192, 256, 0, stream>>>(Xt, out);
}